// Round 12
// baseline (134.544 us; speedup 1.0000x reference)
//
#include <hip/hip_runtime.h>

typedef _Float16 half8  __attribute__((ext_vector_type(8)));
typedef _Float16 half2v __attribute__((ext_vector_type(2)));
typedef float    f32x4  __attribute__((ext_vector_type(4)));

#define BB 16          // bond feature dim
#define NB_B 17        // bond features + bias-one feature
#define BM 64          // edges per block tile
#define PACK_BLKS 34
#define ZERO_BLKS 1024

__device__ __forceinline__ void gll16(const void* g, void* l) {
  __builtin_amdgcn_global_load_lds(
      (const __attribute__((address_space(1))) void*)g,
      (__attribute__((address_space(3))) void*)l, 16, 0, 0);
}

// ktg layout: round r (=b), parity sp, col-frag t, lane, e:
//   half-offset = r*4096 + sp*2048 + t*512 + lane*8 + e
//   value = M2[i(t,lane)][(2r+sp)*32 + (lane>>4)*8 + e]
// with EVEN/ODD column interleave: i(t,l) = (t>>1)*32 + 2*(l&15) + (t&1)
// so a lane's two frag columns (nt=0,1) are ADJACENT output cols.
// M2[i][b*64+j] = kernel[b][i*64+j] (b<16), bias[i*64+j] (b==16).
__global__ void prep(const float* __restrict__ kern, const float* __restrict__ bias,
                     _Float16* __restrict__ ktg, f32x4* __restrict__ out4, int n4) {
  if (blockIdx.x < PACK_BLKS) {
    int g = blockIdx.x * 256 + threadIdx.x;   // one thread per (s, t, lane)
    int s = g >> 8, t = (g >> 6) & 3, l = g & 63;
    int i = (t >> 1) * 32 + 2 * (l & 15) + (t & 1);   // even/odd interleave
    int k0 = s * 32 + (l >> 4) * 8;
    _Float16 v[8];
#pragma unroll
    for (int e = 0; e < 8; ++e) {
      int k = k0 + e, b = k >> 6, j = k & 63;
      float x = (b < BB) ? kern[b * 4096 + i * 64 + j] : bias[i * 64 + j];
      v[e] = (_Float16)x;
    }
    size_t dst = (size_t)(s >> 1) * 4096 + (size_t)(s & 1) * 2048 + t * 512 + l * 8;
    *(half8*)(ktg + dst) = *(const half8*)v;
  } else {
    int i = (blockIdx.x - PACK_BLKS) * 256 + threadIdx.x;
    for (; i < n4; i += ZERO_BLKS * 256) out4[i] = (f32x4){0.f, 0.f, 0.f, 0.f};
  }
}

// Fused: transformed = X @ M2^T with X[e, b*64+j] = bond[e,b]*nb[e,j], then
// atomic segment-sum into out[src(e)].
// Persistent 2-tile blocks: grid = ceil(nTiles/2); block handles tiles
// {bid, bid+grid} serially so tile-2 compute overlaps tile-1's atomic drain.
// BM=64, 4 waves in 2(row)x2(col); A one-shot in regs; B dbuf LDS.
__global__ __launch_bounds__(256, 5)
void edge_gemm(const float* __restrict__ atom, const float* __restrict__ bond,
               const int* __restrict__ pair, const _Float16* __restrict__ ktg,
               float* __restrict__ out, int E, int nTiles) {
  __shared__ __align__(16) _Float16 nb[BM * 64];     // 8 KB, XOR-swizzled
  __shared__ __align__(16) char bbuf[2][8192];       // B double-buffer, 16 KB
  __shared__ _Float16 bndh[NB_B * BM];               // scales [b][row], 2.1 KB
  __shared__ int srcs[BM];
  __shared__ int nbrs[BM];

  const int tid  = threadIdx.x;
  const int lane = tid & 63, wave = tid >> 6;
  const int wm = wave >> 1, wn = wave & 1;   // row-half, col-half
  const int l15 = lane & 15, lg = lane >> 4;

  for (int tile = blockIdx.x; tile < nTiles; tile += gridDim.x) {
    const int e0 = tile * BM;
    __syncthreads();   // prior tile's LDS reads (incl. epilogue srcs) done

    // ---- stage pairs + B round 0 ----
    if (tid < BM) {
      const int e = e0 + tid;
      const bool valid = e < E;
      int2 p2 = valid ? *(const int2*)(pair + 2 * e) : (int2){0, 0};
      srcs[tid] = p2.x;
      nbrs[tid] = p2.y;
    }
    gll16((const char*)ktg + tid * 16,        (char*)bbuf[0] + tid * 16);
    gll16((const char*)ktg + 4096 + tid * 16, (char*)bbuf[0] + 4096 + tid * 16);
    __syncthreads();   // nbrs visible (also drains the B0 stage)

    // ---- bond scales -> bndh[b*64 + row] (f16) ----
    if (tid < BM) {
      const int e = e0 + tid;
      const bool valid = e < E;
      const f32x4* brow = (const f32x4*)(bond + (size_t)e * BB);
#pragma unroll
      for (int q = 0; q < 4; ++q) {
        f32x4 bv = {0.f, 0.f, 0.f, 0.f};
        if (valid) bv = brow[q];
#pragma unroll
        for (int z = 0; z < 4; ++z) bndh[(q * 4 + z) * BM + tid] = (_Float16)bv[z];
      }
      bndh[16 * BM + tid] = valid ? (_Float16)1.0f : (_Float16)0.0f;  // bias-one
    }

    // ---- gather neighbor rows -> nb (f16, XOR-swizzled) ----
#pragma unroll
    for (int it = 0; it < 2; ++it) {
      const int idx = it * 256 + tid;          // 512 = 64 rows x 8 chunks
      const int r = idx >> 3, c8 = idx & 7;
      const int nbr = nbrs[r];
      const bool valid = (e0 + r) < E;
      f32x4 x0 = {0.f,0.f,0.f,0.f}, x1 = {0.f,0.f,0.f,0.f};
      if (valid) {
        const f32x4* arow = (const f32x4*)(atom + (size_t)nbr * 64);
        x0 = arow[2 * c8]; x1 = arow[2 * c8 + 1];
      }
      _Float16 h[8];
      h[0] = (_Float16)x0[0]; h[1] = (_Float16)x0[1]; h[2] = (_Float16)x0[2]; h[3] = (_Float16)x0[3];
      h[4] = (_Float16)x1[0]; h[5] = (_Float16)x1[1]; h[6] = (_Float16)x1[2]; h[7] = (_Float16)x1[3];
      *(half8*)((char*)nb + r * 128 + ((c8 ^ (r & 7)) << 4)) = *(const half8*)h;
    }
    __syncthreads();   // nb + bndh + bbuf[0] ready

    // ---- one-shot A fragments into registers (2 row-tiles x 2 k-parities) ----
    half8 a[2][2];
#pragma unroll
    for (int t = 0; t < 2; ++t) {
      const int r = wm * 32 + t * 16 + l15;
      const int rb = r * 128, sw = (r & 7) << 4;
#pragma unroll
      for (int p = 0; p < 2; ++p)
        a[t][p] = *(const half8*)((const char*)nb + rb + (((p * 4 + lg) << 4) ^ sw));
    }

    f32x4 acc[2][2];
#pragma unroll
    for (int t = 0; t < 2; ++t)
#pragma unroll
      for (int n = 0; n < 2; ++n) acc[t][n] = (f32x4){0.f, 0.f, 0.f, 0.f};

    // ---- K loop: 17 rounds; stage-early, compute from LDS, 1 barrier/round ----
    for (int b = 0; b < NB_B; ++b) {
      if (b + 1 < NB_B) {
        const char* src = (const char*)ktg + (size_t)(b + 1) * 8192;
        char* dst = (char*)bbuf[(b + 1) & 1];
        gll16(src + tid * 16,        dst + tid * 16);
        gll16(src + 4096 + tid * 16, dst + 4096 + tid * 16);
      }
      const _Float16 s0 = bndh[b * BM + wm * 32 + l15];
      const _Float16 s1 = bndh[b * BM + wm * 32 + 16 + l15];
      const half2v sc0 = {s0, s0}, sc1 = {s1, s1};
      const char* bp = (const char*)bbuf[b & 1] + (size_t)(wn * 2) * 1024 + lane * 16;
#pragma unroll
      for (int sp = 0; sp < 2; ++sp) {
        half8 a0 = a[0][sp], a1 = a[1][sp];
        half2v* a0p = (half2v*)&a0; half2v* a1p = (half2v*)&a1;
#pragma unroll
        for (int q = 0; q < 4; ++q) { a0p[q] = a0p[q] * sc0; a1p[q] = a1p[q] * sc1; }
#pragma unroll
        for (int nt = 0; nt < 2; ++nt) {
          const half8 bf = *(const half8*)(bp + sp * 4096 + nt * 1024);
          acc[0][nt] = __builtin_amdgcn_mfma_f32_16x16x32_f16(a0, bf, acc[0][nt], 0, 0, 0);
          acc[1][nt] = __builtin_amdgcn_mfma_f32_16x16x32_f16(a1, bf, acc[1][nt], 0, 0, 0);
        }
      }
      __syncthreads();   // all reads of bbuf[b&1] done; next stage may overwrite
    }

    // ---- epilogue: segment-sum, scalar atomics (fire-and-forget) ----
    // cols 2*l15, 2*l15+1 of the wave's 32-col slice (even/odd interleave).
#pragma unroll
    for (int t = 0; t < 2; ++t) {
#pragma unroll
      for (int rr = 0; rr < 4; ++rr) {
        const int el = wm * 32 + t * 16 + lg * 4 + rr;
        if (e0 + el < E) {
          float* dst = out + (size_t)srcs[el] * 64 + wn * 32 + 2 * l15;
          atomicAdd(dst,     acc[t][0][rr]);
          atomicAdd(dst + 1, acc[t][1][rr]);
        }
      }
    }
  }
}

extern "C" void kernel_launch(void* const* d_in, const int* in_sizes, int n_in,
                              void* d_out, int out_size, void* d_ws, size_t ws_size,
                              hipStream_t stream) {
  const float* atom = (const float*)d_in[0];
  const float* bond = (const float*)d_in[1];
  const int*   pair = (const int*)d_in[2];
  const float* kern = (const float*)d_in[3];
  const float* bias = (const float*)d_in[4];
  float* out = (float*)d_out;
  _Float16* ktg = (_Float16*)d_ws;   // 69,632 halves = 139,264 B

  const int E  = in_sizes[1] / BB;
  const int n4 = out_size / 4;
  const int nTiles = (E + BM - 1) / BM;
  const int grid   = (nTiles + 1) / 2;   // 2 tiles per persistent block

  prep<<<PACK_BLKS + ZERO_BLKS, 256, 0, stream>>>(kern, bias, ktg, (f32x4*)out, n4);
  edge_gemm<<<grid, 256, 0, stream>>>(atom, bond, pair, ktg, out, E, nTiles);
}

// Round 13
// 117.393 us; speedup vs baseline: 1.1461x; 1.1461x over previous
//
#include <hip/hip_runtime.h>

typedef _Float16 half8  __attribute__((ext_vector_type(8)));
typedef _Float16 half2v __attribute__((ext_vector_type(2)));
typedef float    f32x4  __attribute__((ext_vector_type(4)));
typedef float    f32x2  __attribute__((ext_vector_type(2)));
typedef int      i32x4  __attribute__((ext_vector_type(4)));

#define BB 16          // bond feature dim
#define NB_B 17        // bond features + bias-one feature
#define BM 64          // edges per block tile
#define PACK_BLKS 34
#define INIT_BLKS 64

// d_ws layout (ws >= 256 MiB per harness poison):
//   [0)            ktg      139,264 B
//   [1 MiB)        trans    E*64 f32 (25.6 MB)
//   [28 MiB)       head     N int
//   [29 MiB)       next     E int
#define TRANS_OFF (1u << 20)
#define HEAD_OFF  (28u << 20)
#define NEXT_OFF  (29u << 20)

__device__ __forceinline__ void gll16(const void* g, void* l) {
  __builtin_amdgcn_global_load_lds(
      (const __attribute__((address_space(1))) void*)g,
      (__attribute__((address_space(3))) void*)l, 16, 0, 0);
}

// ktg layout: round r (=b), parity sp, col-frag t, lane, e:
//   half-offset = r*4096 + sp*2048 + t*512 + lane*8 + e
//   value = M2[i(t,lane)][(2r+sp)*32 + (lane>>4)*8 + e]
// EVEN/ODD column interleave: i(t,l) = (t>>1)*32 + 2*(l&15) + (t&1)
// so a lane's two frag columns are ADJACENT output cols (f32x2 store).
// M2[i][b*64+j] = kernel[b][i*64+j] (b<16), bias[i*64+j] (b==16).
__global__ void prep(const float* __restrict__ kern, const float* __restrict__ bias,
                     _Float16* __restrict__ ktg, int* __restrict__ head, int n4head) {
  if (blockIdx.x < PACK_BLKS) {
    int g = blockIdx.x * 256 + threadIdx.x;   // one thread per (s, t, lane)
    int s = g >> 8, t = (g >> 6) & 3, l = g & 63;
    int i = (t >> 1) * 32 + 2 * (l & 15) + (t & 1);   // even/odd interleave
    int k0 = s * 32 + (l >> 4) * 8;
    _Float16 v[8];
#pragma unroll
    for (int e = 0; e < 8; ++e) {
      int k = k0 + e, b = k >> 6, j = k & 63;
      float x = (b < BB) ? kern[b * 4096 + i * 64 + j] : bias[i * 64 + j];
      v[e] = (_Float16)x;
    }
    size_t dst = (size_t)(s >> 1) * 4096 + (size_t)(s & 1) * 2048 + t * 512 + l * 8;
    *(half8*)(ktg + dst) = *(const half8*)v;
  } else {
    // init head[] = -1 (empty lists), int4 grid-stride
    i32x4* h4 = (i32x4*)head;
    int i = (blockIdx.x - PACK_BLKS) * 256 + threadIdx.x;
    for (; i < n4head; i += INIT_BLKS * 256) h4[i] = (i32x4){-1, -1, -1, -1};
  }
}

// Fused edge GEMM: transformed[e] = (bond[e] (+bias-one)) applied via
// X @ M2^T, X[e, b*64+j] = bond[e,b]*nb[e,j]. PLAIN stores to trans;
// linked-list push (1 atomicExch/edge) for the gather pass.
// BM=64, 4 waves in 2(row)x2(col); A one-shot in regs; B dbuf LDS.
__global__ __launch_bounds__(256, 5)
void edge_gemm(const float* __restrict__ atom, const float* __restrict__ bond,
               const int* __restrict__ pair, const _Float16* __restrict__ ktg,
               float* __restrict__ trans, int* __restrict__ head,
               int* __restrict__ next, int E) {
  __shared__ __align__(16) _Float16 nb[BM * 64];     // 8 KB, XOR-swizzled
  __shared__ __align__(16) char bbuf[2][8192];       // B double-buffer, 16 KB
  __shared__ _Float16 bndh[NB_B * BM];               // scales [b][row], 2.1 KB
  __shared__ int nbrs[BM];

  const int tid = threadIdx.x;
  const int e0  = blockIdx.x * BM;

  // ---- stage pairs + list push + B round 0 ----
  if (tid < BM) {
    const int e = e0 + tid;
    const bool valid = e < E;
    int2 p2 = valid ? *(const int2*)(pair + 2 * e) : (int2){0, 0};
    nbrs[tid] = p2.y;
    if (valid) next[e] = atomicExch(&head[p2.x], e);   // push edge onto src list
  }
  gll16((const char*)ktg + tid * 16,        (char*)bbuf[0] + tid * 16);
  gll16((const char*)ktg + 4096 + tid * 16, (char*)bbuf[0] + 4096 + tid * 16);
  __syncthreads();   // nbrs visible (also drains the B0 stage)

  // ---- bond scales -> bndh[b*64 + row] (f16) ----
  if (tid < BM) {
    const int e = e0 + tid;
    const bool valid = e < E;
    const f32x4* brow = (const f32x4*)(bond + (size_t)e * BB);
#pragma unroll
    for (int q = 0; q < 4; ++q) {
      f32x4 bv = {0.f, 0.f, 0.f, 0.f};
      if (valid) bv = brow[q];
#pragma unroll
      for (int z = 0; z < 4; ++z) bndh[(q * 4 + z) * BM + tid] = (_Float16)bv[z];
    }
    bndh[16 * BM + tid] = valid ? (_Float16)1.0f : (_Float16)0.0f;  // bias-one
  }

  // ---- gather neighbor rows -> nb (f16, XOR-swizzled) ----
#pragma unroll
  for (int it = 0; it < 2; ++it) {
    const int idx = it * 256 + tid;          // 512 = 64 rows x 8 chunks
    const int r = idx >> 3, c8 = idx & 7;
    const int nbr = nbrs[r];
    const bool valid = (e0 + r) < E;
    f32x4 x0 = {0.f,0.f,0.f,0.f}, x1 = {0.f,0.f,0.f,0.f};
    if (valid) {
      const f32x4* arow = (const f32x4*)(atom + (size_t)nbr * 64);
      x0 = arow[2 * c8]; x1 = arow[2 * c8 + 1];
    }
    _Float16 h[8];
    h[0] = (_Float16)x0[0]; h[1] = (_Float16)x0[1]; h[2] = (_Float16)x0[2]; h[3] = (_Float16)x0[3];
    h[4] = (_Float16)x1[0]; h[5] = (_Float16)x1[1]; h[6] = (_Float16)x1[2]; h[7] = (_Float16)x1[3];
    *(half8*)((char*)nb + r * 128 + ((c8 ^ (r & 7)) << 4)) = *(const half8*)h;
  }
  __syncthreads();   // nb + bndh + bbuf[0] ready

  const int lane = tid & 63, wave = tid >> 6;
  const int wm = wave >> 1, wn = wave & 1;   // row-half, col-half
  const int l15 = lane & 15, lg = lane >> 4;

  // ---- one-shot A fragments into registers (2 row-tiles x 2 k-parities) ----
  half8 a[2][2];
#pragma unroll
  for (int t = 0; t < 2; ++t) {
    const int r = wm * 32 + t * 16 + l15;
    const int rb = r * 128, sw = (r & 7) << 4;
#pragma unroll
    for (int p = 0; p < 2; ++p)
      a[t][p] = *(const half8*)((const char*)nb + rb + (((p * 4 + lg) << 4) ^ sw));
  }

  f32x4 acc[2][2];
#pragma unroll
  for (int t = 0; t < 2; ++t)
#pragma unroll
    for (int n = 0; n < 2; ++n) acc[t][n] = (f32x4){0.f, 0.f, 0.f, 0.f};

  // ---- K loop: 17 rounds; stage-early, compute from LDS, 1 barrier/round ----
  for (int b = 0; b < NB_B; ++b) {
    if (b + 1 < NB_B) {
      const char* src = (const char*)ktg + (size_t)(b + 1) * 8192;
      char* dst = (char*)bbuf[(b + 1) & 1];
      gll16(src + tid * 16,        dst + tid * 16);
      gll16(src + 4096 + tid * 16, dst + 4096 + tid * 16);
    }
    const _Float16 s0 = bndh[b * BM + wm * 32 + l15];
    const _Float16 s1 = bndh[b * BM + wm * 32 + 16 + l15];
    const half2v sc0 = {s0, s0}, sc1 = {s1, s1};
    const char* bp = (const char*)bbuf[b & 1] + (size_t)(wn * 2) * 1024 + lane * 16;
#pragma unroll
    for (int sp = 0; sp < 2; ++sp) {
      half8 a0 = a[0][sp], a1 = a[1][sp];
      half2v* a0p = (half2v*)&a0; half2v* a1p = (half2v*)&a1;
#pragma unroll
      for (int q = 0; q < 4; ++q) { a0p[q] = a0p[q] * sc0; a1p[q] = a1p[q] * sc1; }
#pragma unroll
      for (int nt = 0; nt < 2; ++nt) {
        const half8 bf = *(const half8*)(bp + sp * 4096 + nt * 1024);
        acc[0][nt] = __builtin_amdgcn_mfma_f32_16x16x32_f16(a0, bf, acc[0][nt], 0, 0, 0);
        acc[1][nt] = __builtin_amdgcn_mfma_f32_16x16x32_f16(a1, bf, acc[1][nt], 0, 0, 0);
      }
    }
    __syncthreads();   // all reads of bbuf[b&1] done; next stage may overwrite
  }

  // ---- epilogue: PLAIN coalesced stores (cols 2*l15, 2*l15+1) ----
#pragma unroll
  for (int t = 0; t < 2; ++t) {
#pragma unroll
    for (int rr = 0; rr < 4; ++rr) {
      const int el = wm * 32 + t * 16 + lg * 4 + rr;
      if (e0 + el < E) {
        f32x2 v = {acc[t][0][rr], acc[t][1][rr]};
        *(f32x2*)(trans + (size_t)(e0 + el) * 64 + wn * 32 + 2 * l15) = v;
      }
    }
  }
}

// Segment-sum: one wave per node (lane = col), walk the edge list,
// plain read of transformed rows, write out row exactly once.
__global__ __launch_bounds__(256)
void gather(const float* __restrict__ trans, const int* __restrict__ head,
            const int* __restrict__ next, float* __restrict__ out, int N) {
  const int lane = threadIdx.x & 63;
  const int w    = (blockIdx.x * blockDim.x + threadIdx.x) >> 6;
  const int nw   = (gridDim.x * blockDim.x) >> 6;
  for (int n = w; n < N; n += nw) {
    float acc = 0.f;
    int e = head[n];                       // wave-uniform broadcast load
    while (e >= 0) {
      acc += trans[(size_t)e * 64 + lane]; // coalesced 256 B row
      e = next[e];
    }
    out[(size_t)n * 64 + lane] = acc;
  }
}

extern "C" void kernel_launch(void* const* d_in, const int* in_sizes, int n_in,
                              void* d_out, int out_size, void* d_ws, size_t ws_size,
                              hipStream_t stream) {
  const float* atom = (const float*)d_in[0];
  const float* bond = (const float*)d_in[1];
  const int*   pair = (const int*)d_in[2];
  const float* kern = (const float*)d_in[3];
  const float* bias = (const float*)d_in[4];
  float* out = (float*)d_out;

  _Float16* ktg  = (_Float16*)d_ws;
  float*    trans = (float*)((char*)d_ws + TRANS_OFF);
  int*      head  = (int*)((char*)d_ws + HEAD_OFF);
  int*      next  = (int*)((char*)d_ws + NEXT_OFF);

  const int E = in_sizes[1] / BB;
  const int N = out_size / 64;
  const int n4head = (N + 3) / 4;

  prep<<<PACK_BLKS + INIT_BLKS, 256, 0, stream>>>(kern, bias, ktg, head, n4head);
  edge_gemm<<<(E + BM - 1) / BM, 256, 0, stream>>>(atom, bond, pair, ktg,
                                                   trans, head, next, E);
  gather<<<1024, 256, 0, stream>>>(trans, head, next, out, N);
}